// Round 26
// baseline (291.553 us; speedup 1.0000x reference)
//
#include <hip/hip_runtime.h>
#include <hip/hip_bf16.h>
#include <cstdint>

typedef short short8 __attribute__((ext_vector_type(8)));
typedef short short4v __attribute__((ext_vector_type(4)));
typedef __bf16 bf16x8 __attribute__((ext_vector_type(8)));
typedef float f32x4 __attribute__((ext_vector_type(4)));
typedef unsigned short u16;
typedef unsigned int u32;

#define B_  2
#define N_  4096
#define D_  2048
#define H_  8
#define DH_ 128
#define W_  512
#define M_  (B_*N_)      // 8192
#define INNER_ (H_*DH_)  // 1024

static __device__ __forceinline__ u16 f2bf(float f) {
  u32 u = __float_as_uint(f);
  u32 r = (u + 0x7fffu + ((u >> 16) & 1u)) >> 16;   // RNE
  return (u16)r;
}
static __device__ __forceinline__ float bf2f(u16 u) {
  return __uint_as_float(((u32)u) << 16);
}
static __device__ __forceinline__ f32x4 mfma16(short8 a, short8 b, f32x4 c) {
  return __builtin_amdgcn_mfma_f32_16x16x32_bf16(
      __builtin_bit_cast(bf16x8, a), __builtin_bit_cast(bf16x8, b), c, 0, 0, 0);
}

#define GLOAD_LDS16(g, s) \
  __builtin_amdgcn_global_load_lds((const __attribute__((address_space(1))) void*)(g), \
                                   (__attribute__((address_space(3))) void*)(s), 16, 0, 0)
#define BARRIER() __builtin_amdgcn_s_barrier()
#define SB0 __builtin_amdgcn_sched_barrier(0)
#define WVM4 asm volatile("s_waitcnt vmcnt(4)" ::: "memory")
#define WVM0 asm volatile("s_waitcnt vmcnt(0)" ::: "memory")

// ---------------- convert f32 -> bf16 (x, Wq|Wkv concat, Wo) ----------------
__global__ __launch_bounds__(256) void cvt_kernel(
    const float* __restrict__ x, const float* __restrict__ Wq,
    const float* __restrict__ Wkv, const float* __restrict__ Wo,
    u16* __restrict__ xb, u16* __restrict__ Wcat, u16* __restrict__ Wob) {
  size_t i = ((size_t)blockIdx.x * 256 + threadIdx.x) * 8;
  const float* src; u16* dst; size_t off;
  const size_t SX = 16777216ul, SQ = 2097152ul, SKV = 4194304ul;
  if (i < SX)                { src = x;   dst = xb;             off = i; }
  else if (i < SX+SQ)        { src = Wq;  dst = Wcat;           off = i - SX; }
  else if (i < SX+SQ+SKV)    { src = Wkv; dst = Wcat + 2097152; off = i - SX - SQ; }
  else                       { src = Wo;  dst = Wob;            off = i - SX - SQ - SKV; }
  float4 a = *(const float4*)(src + off);
  float4 b = *(const float4*)(src + off + 4);
  short8 o;
  o[0]=(short)f2bf(a.x); o[1]=(short)f2bf(a.y); o[2]=(short)f2bf(a.z); o[3]=(short)f2bf(a.w);
  o[4]=(short)f2bf(b.x); o[5]=(short)f2bf(b.y); o[6]=(short)f2bf(b.z); o[7]=(short)f2bf(b.w);
  *(short8*)(dst + off) = o;
}

// ======== QK 128x128 GEMM, dim3(16,64) — bx%8 pins B-panels/XCD ============
// bx 0..7: Q -> L2norm*8*q_scale -> qb ; bx 8..15: K -> L2norm*k_scale -> kb.
// pbuf aliases sA (dead after K-loop) -> LDS stays 32768 B.
__global__ __launch_bounds__(256) void gemm_qk(
    const u16* __restrict__ A, const u16* __restrict__ Wcat,
    u16* __restrict__ Dq, u16* __restrict__ Dk,
    const float* __restrict__ qs, const float* __restrict__ ks) {
  __shared__ u16 sA[128*64];
  __shared__ u16 sB[128*64];
  const int K = D_;
  const int bx = blockIdx.x, by = blockIdx.y;   // block->XCD = bx%8
  const int tid = threadIdx.x;
  const int lane = tid & 63, wv = tid >> 6;
  const int wm = wv >> 1, wn = wv & 1;
  const int m0 = by * 128, n0 = bx * 128;
  const int l15 = lane & 15, l4 = lane >> 4;
  f32x4 acc[4][4] = {};

  #pragma unroll 1
  for (int kt = 0; kt < K; kt += 64) {
    __syncthreads();
    #pragma unroll
    for (int r = 0; r < 4; ++r) {          // stage A
      int cf = r*256 + tid;
      int row = cf >> 3, cph = cf & 7;
      int clg = cph ^ (row & 7);
      GLOAD_LDS16(A + (size_t)(m0 + row)*K + kt + clg*8, sA + (size_t)(r*256 + wv*64)*8);
    }
    #pragma unroll
    for (int r = 0; r < 4; ++r) {          // stage B
      int cf = r*256 + tid;
      int row = cf >> 3, cph = cf & 7;
      int clg = cph ^ (row & 7);
      GLOAD_LDS16(Wcat + (size_t)(n0 + row)*K + kt + clg*8, sB + (size_t)(r*256 + wv*64)*8);
    }
    __syncthreads();
    #pragma unroll
    for (int ks2 = 0; ks2 < 2; ++ks2) {
      short8 af[4], bfr[4];
      #pragma unroll
      for (int mf = 0; mf < 4; ++mf) {
        int row = wm*64 + mf*16 + l15;
        int ch = (ks2*4 + l4) ^ (row & 7);
        af[mf] = *(const short8*)(sA + row*64 + ch*8);
      }
      #pragma unroll
      for (int nf = 0; nf < 4; ++nf) {
        int row = wn*64 + nf*16 + l15;
        int ch = (ks2*4 + l4) ^ (row & 7);
        bfr[nf] = *(const short8*)(sB + row*64 + ch*8);
      }
      #pragma unroll
      for (int mf = 0; mf < 4; ++mf)
        #pragma unroll
        for (int nf = 0; nf < 4; ++nf)
          acc[mf][nf] = mfma16(af[mf], bfr[nf], acc[mf][nf]);
    }
  }

  const int sel = bx >> 3;      // 0=q 1=k
  const int h = bx & 7;
  const int b = m0 >> 12;
  // fused qk L2-norm over the full head dim (n-tile == one head)
  float (*pbuf)[128] = (float (*)[128])sA;       // alias dead sA
  __syncthreads();                               // all MFMA reads of sA done
  #pragma unroll
  for (int mf = 0; mf < 4; ++mf)
    #pragma unroll
    for (int j = 0; j < 4; ++j) {
      float ss = acc[mf][0][j]*acc[mf][0][j] + acc[mf][1][j]*acc[mf][1][j]
               + acc[mf][2][j]*acc[mf][2][j] + acc[mf][3][j]*acc[mf][3][j];
      #pragma unroll
      for (int off = 1; off <= 8; off <<= 1) ss += __shfl_xor(ss, off);
      if (l15 == 0) pbuf[wn][wm*64 + mf*16 + l4*4 + j] = ss;
    }
  __syncthreads();
  u16* dst = sel == 0 ? Dq : Dk;
  const float* sc = sel == 0 ? qs : ks;
  #pragma unroll
  for (int mf = 0; mf < 4; ++mf)
    #pragma unroll
    for (int j = 0; j < 4; ++j) {
      int rloc = wm*64 + mf*16 + l4*4 + j;
      float ss = pbuf[0][rloc] + pbuf[1][rloc];
      float inv = 1.0f / fmaxf(sqrtf(ss), 1e-12f);
      if (sel == 0) inv *= 8.0f;                   // fold qk_scale SCALE
      int n = (m0 + rloc) & (N_ - 1);
      size_t base = ((size_t)(b*H_ + h)*N_ + n) << 7;
      #pragma unroll
      for (int nf = 0; nf < 4; ++nf) {
        int d = wn*64 + nf*16 + l15;
        dst[base + d] = f2bf(acc[mf][nf][j] * inv * sc[d]);
      }
    }
}

// ======== V 128x128 GEMM, dim3(8,64) — transpose-only epilogue (lean VGPR) ==
__global__ __launch_bounds__(256) void gemm_v(
    const u16* __restrict__ A, const u16* __restrict__ Wcat,
    u16* __restrict__ Dv) {
  __shared__ u16 sA[128*64];
  __shared__ u16 sB[128*64];
  const int K = D_;
  const int bx = blockIdx.x, by = blockIdx.y;   // block->XCD = bx%8
  const int tid = threadIdx.x;
  const int lane = tid & 63, wv = tid >> 6;
  const int wm = wv >> 1, wn = wv & 1;
  const int m0 = by * 128, n0 = (bx + 16) * 128;  // V weight rows 2048..3071
  const int l15 = lane & 15, l4 = lane >> 4;
  f32x4 acc[4][4] = {};

  #pragma unroll 1
  for (int kt = 0; kt < K; kt += 64) {
    __syncthreads();
    #pragma unroll
    for (int r = 0; r < 4; ++r) {          // stage A
      int cf = r*256 + tid;
      int row = cf >> 3, cph = cf & 7;
      int clg = cph ^ (row & 7);
      GLOAD_LDS16(A + (size_t)(m0 + row)*K + kt + clg*8, sA + (size_t)(r*256 + wv*64)*8);
    }
    #pragma unroll
    for (int r = 0; r < 4; ++r) {          // stage B
      int cf = r*256 + tid;
      int row = cf >> 3, cph = cf & 7;
      int clg = cph ^ (row & 7);
      GLOAD_LDS16(Wcat + (size_t)(n0 + row)*K + kt + clg*8, sB + (size_t)(r*256 + wv*64)*8);
    }
    __syncthreads();
    #pragma unroll
    for (int ks2 = 0; ks2 < 2; ++ks2) {
      short8 af[4], bfr[4];
      #pragma unroll
      for (int mf = 0; mf < 4; ++mf) {
        int row = wm*64 + mf*16 + l15;
        int ch = (ks2*4 + l4) ^ (row & 7);
        af[mf] = *(const short8*)(sA + row*64 + ch*8);
      }
      #pragma unroll
      for (int nf = 0; nf < 4; ++nf) {
        int row = wn*64 + nf*16 + l15;
        int ch = (ks2*4 + l4) ^ (row & 7);
        bfr[nf] = *(const short8*)(sB + row*64 + ch*8);
      }
      #pragma unroll
      for (int mf = 0; mf < 4; ++mf)
        #pragma unroll
        for (int nf = 0; nf < 4; ++nf)
          acc[mf][nf] = mfma16(af[mf], bfr[nf], acc[mf][nf]);
    }
  }

  // fused V transpose: vT[(b*H+h)*128 + d][n]
  const int h = bx;
  const int b = m0 >> 12;
  const int bh = b*H_ + h;
  #pragma unroll
  for (int mf = 0; mf < 4; ++mf)
    #pragma unroll
    for (int nf = 0; nf < 4; ++nf) {
      int d = wn*64 + nf*16 + l15;
      int n = ((m0 & (N_ - 1)) + wm*64 + mf*16 + l4*4);
      short4v pk;
      pk[0] = (short)f2bf(acc[mf][nf][0]);
      pk[1] = (short)f2bf(acc[mf][nf][1]);
      pk[2] = (short)f2bf(acc[mf][nf][2]);
      pk[3] = (short)f2bf(acc[mf][nf][3]);
      *(short4v*)(Dv + ((size_t)bh*128 + d)*N_ + n) = pk;
    }
}

// ======== proj 128x128 GEMM, dim3(16,64) — bx%8 pins B-panels/XCD ==========
__global__ __launch_bounds__(256) void gemm_proj(
    const u16* __restrict__ A, const u16* __restrict__ Bw,
    float* __restrict__ Cf) {
  __shared__ u16 sA[128*64];
  __shared__ u16 sB[128*64];
  const int K = INNER_;
  const int bx = blockIdx.x, by = blockIdx.y;
  const int tid = threadIdx.x;
  const int lane = tid & 63, wv = tid >> 6;
  const int wm = wv >> 1, wn = wv & 1;
  const int m0 = by * 128, n0 = bx * 128;
  const int l15 = lane & 15, l4 = lane >> 4;
  f32x4 acc[4][4] = {};

  #pragma unroll 1
  for (int kt = 0; kt < K; kt += 64) {
    __syncthreads();
    #pragma unroll
    for (int r = 0; r < 4; ++r) {
      int cf = r*256 + tid;
      int row = cf >> 3, cph = cf & 7;
      int clg = cph ^ (row & 7);
      GLOAD_LDS16(A + (size_t)(m0 + row)*K + kt + clg*8, sA + (size_t)(r*256 + wv*64)*8);
    }
    #pragma unroll
    for (int r = 0; r < 4; ++r) {
      int cf = r*256 + tid;
      int row = cf >> 3, cph = cf & 7;
      int clg = cph ^ (row & 7);
      GLOAD_LDS16(Bw + (size_t)(n0 + row)*K + kt + clg*8, sB + (size_t)(r*256 + wv*64)*8);
    }
    __syncthreads();
    #pragma unroll
    for (int ks2 = 0; ks2 < 2; ++ks2) {
      short8 af[4], bfr[4];
      #pragma unroll
      for (int mf = 0; mf < 4; ++mf) {
        int row = wm*64 + mf*16 + l15;
        int ch = (ks2*4 + l4) ^ (row & 7);
        af[mf] = *(const short8*)(sA + row*64 + ch*8);
      }
      #pragma unroll
      for (int nf = 0; nf < 4; ++nf) {
        int row = wn*64 + nf*16 + l15;
        int ch = (ks2*4 + l4) ^ (row & 7);
        bfr[nf] = *(const short8*)(sB + row*64 + ch*8);
      }
      #pragma unroll
      for (int mf = 0; mf < 4; ++mf)
        #pragma unroll
        for (int nf = 0; nf < 4; ++nf)
          acc[mf][nf] = mfma16(af[mf], bfr[nf], acc[mf][nf]);
    }
  }

  #pragma unroll
  for (int mf = 0; mf < 4; ++mf)
    #pragma unroll
    for (int nf = 0; nf < 4; ++nf)
      #pragma unroll
      for (int j = 0; j < 4; ++j) {
        int m = m0 + wm*64 + mf*16 + l4*4 + j;
        int nn = n0 + wn*64 + nf*16 + l15;
        Cf[(size_t)m*D_ + nn] = acc[mf][nf][j];
      }
}

// ---------------- gates: sigmoid(xb @ Wg^T + bg), (B*N, 8) f32 (bf16 input) --
__global__ __launch_bounds__(256) void gates_kernel(
    const u16* __restrict__ xb, const float* __restrict__ Wg,
    const float* __restrict__ bg, float* __restrict__ gates) {
  int m = blockIdx.x;
  int tid = threadIdx.x;
  const u16* xr = xb + (size_t)m * D_;
  float acc[8] = {};
  for (int d0 = tid*8; d0 < D_; d0 += 256*8) {
    short8 xv8 = *(const short8*)(xr + d0);
    #pragma unroll
    for (int e = 0; e < 8; ++e) {
      float xv = bf2f((u16)xv8[e]);
      #pragma unroll
      for (int h = 0; h < 8; ++h) acc[h] = fmaf(xv, Wg[h*D_ + d0 + e], acc[h]);
    }
  }
  #pragma unroll
  for (int h = 0; h < 8; ++h)
    #pragma unroll
    for (int off = 32; off >= 1; off >>= 1) acc[h] += __shfl_xor(acc[h], off);
  __shared__ float red[4][8];
  int lane = tid & 63, wv = tid >> 6;
  if (lane == 0) {
    #pragma unroll
    for (int h = 0; h < 8; ++h) red[wv][h] = acc[h];
  }
  __syncthreads();
  if (tid < 8) {
    float vsum = red[0][tid] + red[1][tid] + red[2][tid] + red[3][tid] + bg[tid];
    gates[(size_t)m*8 + tid] = 1.0f / (1.0f + __expf(-vsum));
  }
}

// ---------------- windowed flash attention + gating -> o (B*N, 1024) bf16 ----
// 8 waves x 16 q-rows; K/V double-buffered (80 KB dynamic LDS, 2 blocks/CU);
// counted vmcnt(4) pipeline (T3/T4), raw s_barrier, defer-max (T13, THR=8).
__global__ __launch_bounds__(512, 4) void attn_kernel(
    const u16* __restrict__ q, const u16* __restrict__ k,
    const u16* __restrict__ vT, const float* __restrict__ gates,
    u16* __restrict__ o) {
  extern __shared__ u16 alds[];
  u16* sK = alds;                 // [2][64*128] u16
  u16* sV = alds + 16384;        // [2][128*64] u16
  const int bid = blockIdx.x;
  const int t = bid & 3;
  const int c = (bid >> 2) & 7;
  const int bh = bid >> 5;
  const int b = bh >> 3, h = bh & 7;
  const int i0 = c*W_ + t*128;
  const int tid = threadIdx.x;
  const int lane = tid & 63, wv = tid >> 6;   // wv 0..7, 16 q-rows each
  const int l15 = lane & 15, l4 = lane >> 4;
  u16* sPw = alds + 32768 + wv*1024;          // per-wave P: 16x64 u16

#define STAGE_KV(KT, PB) do { \
    const int _j0 = i0 - 512 + (KT)*64; \
    u16* _dK = sK + (PB)*8192; \
    u16* _dV = sV + (PB)*8192; \
    _Pragma("unroll") for (int r = 0; r < 2; ++r) { \
      int cf = r*512 + tid; int row = cf >> 4, cph = cf & 15; \
      int clg = cph ^ (row & 15); \
      GLOAD_LDS16(k + (((size_t)bh*N_ + _j0 + row) << 7) + clg*8, _dK + (size_t)(r*512 + wv*64)*8); \
    } \
    _Pragma("unroll") for (int r = 0; r < 2; ++r) { \
      int cf = r*512 + tid; int row = cf >> 3, cph = cf & 7; \
      int clg = cph ^ (row & 7); \
      GLOAD_LDS16(vT + ((size_t)bh*128 + row)*N_ + _j0 + clg*8, _dV + (size_t)(r*512 + wv*64)*8); \
    } \
  } while(0)

  // Q fragments: wave's 16 rows (already *q_scale*8 from fused norm)
  short8 qf[4];
  const u16* qbase = q + (((size_t)bh*N_ + i0 + wv*16) << 7);
  #pragma unroll
  for (int ks = 0; ks < 4; ++ks)
    qf[ks] = *(const short8*)(qbase + l15*128 + ks*32 + l4*8);

  float mrow[4], lrow[4];
  f32x4 oacc[8];
  #pragma unroll
  for (int j = 0; j < 4; ++j) { mrow[j] = -1e30f; lrow[j] = 0.f; }
  #pragma unroll
  for (int df = 0; df < 8; ++df) oacc[df] = (f32x4){0.f,0.f,0.f,0.f};

  const int kt0 = (i0 >= 512) ? 0 : ((512 - i0) >> 6);
  STAGE_KV(kt0, 0);

  #pragma unroll 1
  for (int kt = kt0; kt < 10; ++kt) {
    const int pb = (kt - kt0) & 1;
    if (kt < 9) { STAGE_KV(kt + 1, pb ^ 1); WVM4; } else { WVM0; }
    BARRIER(); SB0;                          // buf pb published to all waves

    const int base = 512 - kt*64;            // dist = base + r - s
    const int rmin = wv*16;
    if (base + rmin + 15 >= 0 && base + rmin - 63 <= 512) {
      const u16* cK = sK + pb*8192;
      const u16* cV = sV + pb*8192;

      f32x4 s[4];
      #pragma unroll
      for (int nf = 0; nf < 4; ++nf) s[nf] = (f32x4){0.f,0.f,0.f,0.f};
      #pragma unroll
      for (int ks = 0; ks < 4; ++ks) {
        short8 kb[4];
        #pragma unroll
        for (int nf = 0; nf < 4; ++nf) {
          int row = nf*16 + l15;
          int ch = (ks*4 + l4) ^ (row & 15);
          kb[nf] = *(const short8*)(cK + row*128 + ch*8);
        }
        #pragma unroll
        for (int nf = 0; nf < 4; ++nf)
          s[nf] = mfma16(qf[ks], kb[nf], s[nf]);
      }

      if (kt < 2 || kt > 7) {                // edge tiles: 0 <= dist <= 512
        #pragma unroll
        for (int nf = 0; nf < 4; ++nf)
          #pragma unroll
          for (int j = 0; j < 4; ++j) {
            int r = rmin + l4*4 + j;
            int sidx = nf*16 + l15;
            int dist = base + r - sidx;
            if (dist < 0 || dist > 512) s[nf][j] = -1e30f;
          }
      }

      #pragma unroll
      for (int j = 0; j < 4; ++j) {
        float mx = fmaxf(fmaxf(s[0][j], s[1][j]), fmaxf(s[2][j], s[3][j]));
        #pragma unroll
        for (int off = 1; off <= 8; off <<= 1) mx = fmaxf(mx, __shfl_xor(mx, off));
        if (!__all(mx <= mrow[j] + 8.0f)) {  // defer-max: rescale only on growth
          float mnew = fmaxf(mrow[j], mx);
          float scal = __expf(mrow[j] - mnew);
          mrow[j] = mnew;
          lrow[j] *= scal;
          #pragma unroll
          for (int df = 0; df < 8; ++df) oacc[df][j] *= scal;
        }
        float m = mrow[j];
        float ls = 0.f;
        #pragma unroll
        for (int nf = 0; nf < 4; ++nf) {
          float p = __expf(s[nf][j] - m);
          s[nf][j] = p;
          ls += p;
        }
        #pragma unroll
        for (int off = 1; off <= 8; off <<= 1) ls += __shfl_xor(ls, off);
        lrow[j] += ls;
        int prow = l4*4 + j;
        #pragma unroll
        for (int nf = 0; nf < 4; ++nf) {
          int pcol = nf*16 + l15;
          int ch = (pcol >> 3) ^ (prow & 7);
          sPw[prow*64 + ch*8 + (pcol & 7)] = f2bf(s[nf][j]);
        }
      }

      #pragma unroll
      for (int ks2 = 0; ks2 < 2; ++ks2) {
        short8 pa;
        {
          int ch = (ks2*4 + l4) ^ (l15 & 7);
          pa = *(const short8*)(sPw + l15*64 + ch*8);
        }
        #pragma unroll
        for (int df = 0; df < 8; ++df) {
          int vd = df*16 + l15;
          int ch2 = (ks2*4 + l4) ^ (vd & 7);
          short8 vb = *(const short8*)(cV + vd*64 + ch2*8);
          oacc[df] = mfma16(pa, vb, oacc[df]);
        }
      }
    }
    BARRIER();                               // readers of buf pb done
  }

  #pragma unroll
  for (int j = 0; j < 4; ++j) {
    int r = wv*16 + l4*4 + j;
    int i = i0 + r;
    float f = (1.0f / lrow[j]) * gates[((size_t)b*N_ + i)*8 + h];
    #pragma unroll
    for (int df = 0; df < 8; ++df)
      o[((size_t)b*N_ + i)*INNER_ + h*128 + df*16 + l15] = f2bf(oacc[df][j] * f);
  }
#undef STAGE_KV
}

// ---------------------------------------------------------------------------
extern "C" void kernel_launch(void* const* d_in, const int* in_sizes, int n_in,
                              void* d_out, int out_size, void* d_ws, size_t ws_size,
                              hipStream_t stream) {
  const float* x       = (const float*)d_in[0];
  const float* Wq      = (const float*)d_in[1];
  const float* Wkv     = (const float*)d_in[2];
  const float* q_scale = (const float*)d_in[3];
  const float* k_scale = (const float*)d_in[4];
  const float* Wg      = (const float*)d_in[5];
  const float* bg      = (const float*)d_in[6];
  const float* Wo      = (const float*)d_in[7];
  float* out = (float*)d_out;

  u16* qb  = (u16*)d_out;            // q,k,vT inside d_out (50.3 MB of 67 MB)
  u16* kb  = qb + 8388608;
  u16* vTb = kb + 8388608;

  char* w = (char*)d_ws;
  u16* xb   = (u16*)w;               // 33,554,432 B
  u16* ob   = (u16*)w;               // aliases xb (xb dead after gates)
  u16* Wcat = (u16*)(w + 33554432);  // 12,582,912 B
  u16* Wob  = (u16*)(w + 46137344);  // 4,194,304 B
  float* gb = (float*)(w + 50331648);// 262,144 B
  (void)in_sizes; (void)n_in; (void)out_size; (void)ws_size;

  hipFuncSetAttribute((const void*)attn_kernel,
                      hipFuncAttributeMaxDynamicSharedMemorySize, 81920);

  cvt_kernel<<<12288, 256, 0, stream>>>(x, Wq, Wkv, Wo, xb, Wcat, Wob);
  gemm_v<<<dim3(8, 64), 256, 0, stream>>>(xb, Wcat, vTb);
  gemm_qk<<<dim3(16, 64), 256, 0, stream>>>(xb, Wcat, qb, kb, q_scale, k_scale);
  gates_kernel<<<8192, 256, 0, stream>>>(xb, Wg, bg, gb);
  attn_kernel<<<512, 512, 81920, stream>>>(qb, kb, vTb, gb, ob);
  gemm_proj<<<dim3(16, 64), 256, 0, stream>>>(ob, Wob, out);
}

// Round 27
// 270.055 us; speedup vs baseline: 1.0796x; 1.0796x over previous
//
#include <hip/hip_runtime.h>
#include <hip/hip_bf16.h>
#include <cstdint>

typedef short short8 __attribute__((ext_vector_type(8)));
typedef short short4v __attribute__((ext_vector_type(4)));
typedef __bf16 bf16x8 __attribute__((ext_vector_type(8)));
typedef float f32x4 __attribute__((ext_vector_type(4)));
typedef unsigned short u16;
typedef unsigned int u32;

#define B_  2
#define N_  4096
#define D_  2048
#define H_  8
#define DH_ 128
#define W_  512
#define M_  (B_*N_)      // 8192
#define INNER_ (H_*DH_)  // 1024

static __device__ __forceinline__ u16 f2bf(float f) {
  u32 u = __float_as_uint(f);
  u32 r = (u + 0x7fffu + ((u >> 16) & 1u)) >> 16;   // RNE
  return (u16)r;
}
static __device__ __forceinline__ float bf2f(u16 u) {
  return __uint_as_float(((u32)u) << 16);
}
static __device__ __forceinline__ f32x4 mfma16(short8 a, short8 b, f32x4 c) {
  return __builtin_amdgcn_mfma_f32_16x16x32_bf16(
      __builtin_bit_cast(bf16x8, a), __builtin_bit_cast(bf16x8, b), c, 0, 0, 0);
}

#define GLOAD_LDS16(g, s) \
  __builtin_amdgcn_global_load_lds((const __attribute__((address_space(1))) void*)(g), \
                                   (__attribute__((address_space(3))) void*)(s), 16, 0, 0)
#define BARRIER() __builtin_amdgcn_s_barrier()
#define SB0 __builtin_amdgcn_sched_barrier(0)
#define WVM4 asm volatile("s_waitcnt vmcnt(4)" ::: "memory")
#define WVM0 asm volatile("s_waitcnt vmcnt(0)" ::: "memory")

// ---------------- convert f32 -> bf16 (x, Wq|Wkv concat, Wo) ----------------
__global__ __launch_bounds__(256) void cvt_kernel(
    const float* __restrict__ x, const float* __restrict__ Wq,
    const float* __restrict__ Wkv, const float* __restrict__ Wo,
    u16* __restrict__ xb, u16* __restrict__ Wcat, u16* __restrict__ Wob) {
  size_t i = ((size_t)blockIdx.x * 256 + threadIdx.x) * 8;
  const float* src; u16* dst; size_t off;
  const size_t SX = 16777216ul, SQ = 2097152ul, SKV = 4194304ul;
  if (i < SX)                { src = x;   dst = xb;             off = i; }
  else if (i < SX+SQ)        { src = Wq;  dst = Wcat;           off = i - SX; }
  else if (i < SX+SQ+SKV)    { src = Wkv; dst = Wcat + 2097152; off = i - SX - SQ; }
  else                       { src = Wo;  dst = Wob;            off = i - SX - SQ - SKV; }
  float4 a = *(const float4*)(src + off);
  float4 b = *(const float4*)(src + off + 4);
  short8 o;
  o[0]=(short)f2bf(a.x); o[1]=(short)f2bf(a.y); o[2]=(short)f2bf(a.z); o[3]=(short)f2bf(a.w);
  o[4]=(short)f2bf(b.x); o[5]=(short)f2bf(b.y); o[6]=(short)f2bf(b.z); o[7]=(short)f2bf(b.w);
  *(short8*)(dst + off) = o;
}

// ======== fused QKV 128x128 GEMM, dim3(24,64) — bx%8 pins B-panels/XCD =====
// bx 0..7: Q -> L2norm*8*q_scale -> qb ; bx 8..15: K -> L2norm*k_scale -> kb ;
// bx 16..23: V -> transposed -> vT (B*H,128,N).
// pbuf aliases sA (dead after K-loop) -> LDS stays 32768 B.
__global__ __launch_bounds__(256) void gemm_qkv(
    const u16* __restrict__ A, const u16* __restrict__ Wcat,
    u16* __restrict__ Dq, u16* __restrict__ Dk, u16* __restrict__ Dv,
    const float* __restrict__ qs, const float* __restrict__ ks) {
  __shared__ u16 sA[128*64];
  __shared__ u16 sB[128*64];
  const int K = D_;
  const int bx = blockIdx.x, by = blockIdx.y;   // block->XCD = bx%8
  const int tid = threadIdx.x;
  const int lane = tid & 63, wv = tid >> 6;
  const int wm = wv >> 1, wn = wv & 1;
  const int m0 = by * 128, n0 = bx * 128;
  const int l15 = lane & 15, l4 = lane >> 4;
  f32x4 acc[4][4] = {};

  #pragma unroll 1
  for (int kt = 0; kt < K; kt += 64) {
    __syncthreads();
    #pragma unroll
    for (int r = 0; r < 4; ++r) {          // stage A
      int cf = r*256 + tid;
      int row = cf >> 3, cph = cf & 7;
      int clg = cph ^ (row & 7);
      GLOAD_LDS16(A + (size_t)(m0 + row)*K + kt + clg*8, sA + (size_t)(r*256 + wv*64)*8);
    }
    #pragma unroll
    for (int r = 0; r < 4; ++r) {          // stage B
      int cf = r*256 + tid;
      int row = cf >> 3, cph = cf & 7;
      int clg = cph ^ (row & 7);
      GLOAD_LDS16(Wcat + (size_t)(n0 + row)*K + kt + clg*8, sB + (size_t)(r*256 + wv*64)*8);
    }
    __syncthreads();
    #pragma unroll
    for (int ks2 = 0; ks2 < 2; ++ks2) {
      short8 af[4], bfr[4];
      #pragma unroll
      for (int mf = 0; mf < 4; ++mf) {
        int row = wm*64 + mf*16 + l15;
        int ch = (ks2*4 + l4) ^ (row & 7);
        af[mf] = *(const short8*)(sA + row*64 + ch*8);
      }
      #pragma unroll
      for (int nf = 0; nf < 4; ++nf) {
        int row = wn*64 + nf*16 + l15;
        int ch = (ks2*4 + l4) ^ (row & 7);
        bfr[nf] = *(const short8*)(sB + row*64 + ch*8);
      }
      #pragma unroll
      for (int mf = 0; mf < 4; ++mf)
        #pragma unroll
        for (int nf = 0; nf < 4; ++nf)
          acc[mf][nf] = mfma16(af[mf], bfr[nf], acc[mf][nf]);
    }
  }

  const int sel = bx >> 3;      // 0=q 1=k 2=v
  const int h = bx & 7;
  const int b = m0 >> 12;
  if (sel <= 1) {
    // fused qk L2-norm over the full head dim (n-tile == one head)
    float (*pbuf)[128] = (float (*)[128])sA;       // alias dead sA
    __syncthreads();                               // all MFMA reads of sA done
    #pragma unroll
    for (int mf = 0; mf < 4; ++mf)
      #pragma unroll
      for (int j = 0; j < 4; ++j) {
        float ss = acc[mf][0][j]*acc[mf][0][j] + acc[mf][1][j]*acc[mf][1][j]
                 + acc[mf][2][j]*acc[mf][2][j] + acc[mf][3][j]*acc[mf][3][j];
        #pragma unroll
        for (int off = 1; off <= 8; off <<= 1) ss += __shfl_xor(ss, off);
        if (l15 == 0) pbuf[wn][wm*64 + mf*16 + l4*4 + j] = ss;
      }
    __syncthreads();
    u16* dst = sel == 0 ? Dq : Dk;
    const float* sc = sel == 0 ? qs : ks;
    #pragma unroll
    for (int mf = 0; mf < 4; ++mf)
      #pragma unroll
      for (int j = 0; j < 4; ++j) {
        int rloc = wm*64 + mf*16 + l4*4 + j;
        float ss = pbuf[0][rloc] + pbuf[1][rloc];
        float inv = 1.0f / fmaxf(sqrtf(ss), 1e-12f);
        if (sel == 0) inv *= 8.0f;                   // fold qk_scale SCALE
        int n = (m0 + rloc) & (N_ - 1);
        size_t base = ((size_t)(b*H_ + h)*N_ + n) << 7;
        #pragma unroll
        for (int nf = 0; nf < 4; ++nf) {
          int d = wn*64 + nf*16 + l15;
          dst[base + d] = f2bf(acc[mf][nf][j] * inv * sc[d]);
        }
      }
  } else {
    // fused V transpose: vT[(b*H+h)*128 + d][n]
    const int bh = b*H_ + h;
    #pragma unroll
    for (int mf = 0; mf < 4; ++mf)
      #pragma unroll
      for (int nf = 0; nf < 4; ++nf) {
        int d = wn*64 + nf*16 + l15;
        int n = ((m0 & (N_ - 1)) + wm*64 + mf*16 + l4*4);
        short4v pk;
        pk[0] = (short)f2bf(acc[mf][nf][0]);
        pk[1] = (short)f2bf(acc[mf][nf][1]);
        pk[2] = (short)f2bf(acc[mf][nf][2]);
        pk[3] = (short)f2bf(acc[mf][nf][3]);
        *(short4v*)(Dv + ((size_t)bh*128 + d)*N_ + n) = pk;
      }
  }
}

// ======== proj 128x128 GEMM, dim3(16,64) — bx%8 pins B-panels/XCD ==========
__global__ __launch_bounds__(256) void gemm_proj(
    const u16* __restrict__ A, const u16* __restrict__ Bw,
    float* __restrict__ Cf) {
  __shared__ u16 sA[128*64];
  __shared__ u16 sB[128*64];
  const int K = INNER_;
  const int bx = blockIdx.x, by = blockIdx.y;
  const int tid = threadIdx.x;
  const int lane = tid & 63, wv = tid >> 6;
  const int wm = wv >> 1, wn = wv & 1;
  const int m0 = by * 128, n0 = bx * 128;
  const int l15 = lane & 15, l4 = lane >> 4;
  f32x4 acc[4][4] = {};

  #pragma unroll 1
  for (int kt = 0; kt < K; kt += 64) {
    __syncthreads();
    #pragma unroll
    for (int r = 0; r < 4; ++r) {
      int cf = r*256 + tid;
      int row = cf >> 3, cph = cf & 7;
      int clg = cph ^ (row & 7);
      GLOAD_LDS16(A + (size_t)(m0 + row)*K + kt + clg*8, sA + (size_t)(r*256 + wv*64)*8);
    }
    #pragma unroll
    for (int r = 0; r < 4; ++r) {
      int cf = r*256 + tid;
      int row = cf >> 3, cph = cf & 7;
      int clg = cph ^ (row & 7);
      GLOAD_LDS16(Bw + (size_t)(n0 + row)*K + kt + clg*8, sB + (size_t)(r*256 + wv*64)*8);
    }
    __syncthreads();
    #pragma unroll
    for (int ks2 = 0; ks2 < 2; ++ks2) {
      short8 af[4], bfr[4];
      #pragma unroll
      for (int mf = 0; mf < 4; ++mf) {
        int row = wm*64 + mf*16 + l15;
        int ch = (ks2*4 + l4) ^ (row & 7);
        af[mf] = *(const short8*)(sA + row*64 + ch*8);
      }
      #pragma unroll
      for (int nf = 0; nf < 4; ++nf) {
        int row = wn*64 + nf*16 + l15;
        int ch = (ks2*4 + l4) ^ (row & 7);
        bfr[nf] = *(const short8*)(sB + row*64 + ch*8);
      }
      #pragma unroll
      for (int mf = 0; mf < 4; ++mf)
        #pragma unroll
        for (int nf = 0; nf < 4; ++nf)
          acc[mf][nf] = mfma16(af[mf], bfr[nf], acc[mf][nf]);
    }
  }

  #pragma unroll
  for (int mf = 0; mf < 4; ++mf)
    #pragma unroll
    for (int nf = 0; nf < 4; ++nf)
      #pragma unroll
      for (int j = 0; j < 4; ++j) {
        int m = m0 + wm*64 + mf*16 + l4*4 + j;
        int nn = n0 + wn*64 + nf*16 + l15;
        Cf[(size_t)m*D_ + nn] = acc[mf][nf][j];
      }
}

// ---------------- gates: sigmoid(xb @ Wg^T + bg), (B*N, 8) f32 (bf16 input) --
__global__ __launch_bounds__(256) void gates_kernel(
    const u16* __restrict__ xb, const float* __restrict__ Wg,
    const float* __restrict__ bg, float* __restrict__ gates) {
  int m = blockIdx.x;
  int tid = threadIdx.x;
  const u16* xr = xb + (size_t)m * D_;
  float acc[8] = {};
  for (int d0 = tid*8; d0 < D_; d0 += 256*8) {
    short8 xv8 = *(const short8*)(xr + d0);
    #pragma unroll
    for (int e = 0; e < 8; ++e) {
      float xv = bf2f((u16)xv8[e]);
      #pragma unroll
      for (int h = 0; h < 8; ++h) acc[h] = fmaf(xv, Wg[h*D_ + d0 + e], acc[h]);
    }
  }
  #pragma unroll
  for (int h = 0; h < 8; ++h)
    #pragma unroll
    for (int off = 32; off >= 1; off >>= 1) acc[h] += __shfl_xor(acc[h], off);
  __shared__ float red[4][8];
  int lane = tid & 63, wv = tid >> 6;
  if (lane == 0) {
    #pragma unroll
    for (int h = 0; h < 8; ++h) red[wv][h] = acc[h];
  }
  __syncthreads();
  if (tid < 8) {
    float vsum = red[0][tid] + red[1][tid] + red[2][tid] + red[3][tid] + bg[tid];
    gates[(size_t)m*8 + tid] = 1.0f / (1.0f + __expf(-vsum));
  }
}

// ---------------- windowed flash attention + gating -> o (B*N, 1024) bf16 ----
// 8 waves x 16 q-rows; K/V double-buffered (80 KB dynamic LDS, 2 blocks/CU);
// counted vmcnt(4) pipeline (T3/T4), raw s_barrier, defer-max (T13, THR=8).
__global__ __launch_bounds__(512, 4) void attn_kernel(
    const u16* __restrict__ q, const u16* __restrict__ k,
    const u16* __restrict__ vT, const float* __restrict__ gates,
    u16* __restrict__ o) {
  extern __shared__ u16 alds[];
  u16* sK = alds;                 // [2][64*128] u16
  u16* sV = alds + 16384;        // [2][128*64] u16
  const int bid = blockIdx.x;
  const int t = bid & 3;
  const int c = (bid >> 2) & 7;
  const int bh = bid >> 5;
  const int b = bh >> 3, h = bh & 7;
  const int i0 = c*W_ + t*128;
  const int tid = threadIdx.x;
  const int lane = tid & 63, wv = tid >> 6;   // wv 0..7, 16 q-rows each
  const int l15 = lane & 15, l4 = lane >> 4;
  u16* sPw = alds + 32768 + wv*1024;          // per-wave P: 16x64 u16

#define STAGE_KV(KT, PB) do { \
    const int _j0 = i0 - 512 + (KT)*64; \
    u16* _dK = sK + (PB)*8192; \
    u16* _dV = sV + (PB)*8192; \
    _Pragma("unroll") for (int r = 0; r < 2; ++r) { \
      int cf = r*512 + tid; int row = cf >> 4, cph = cf & 15; \
      int clg = cph ^ (row & 15); \
      GLOAD_LDS16(k + (((size_t)bh*N_ + _j0 + row) << 7) + clg*8, _dK + (size_t)(r*512 + wv*64)*8); \
    } \
    _Pragma("unroll") for (int r = 0; r < 2; ++r) { \
      int cf = r*512 + tid; int row = cf >> 3, cph = cf & 7; \
      int clg = cph ^ (row & 7); \
      GLOAD_LDS16(vT + ((size_t)bh*128 + row)*N_ + _j0 + clg*8, _dV + (size_t)(r*512 + wv*64)*8); \
    } \
  } while(0)

  // Q fragments: wave's 16 rows (already *q_scale*8 from fused norm)
  short8 qf[4];
  const u16* qbase = q + (((size_t)bh*N_ + i0 + wv*16) << 7);
  #pragma unroll
  for (int ks = 0; ks < 4; ++ks)
    qf[ks] = *(const short8*)(qbase + l15*128 + ks*32 + l4*8);

  float mrow[4], lrow[4];
  f32x4 oacc[8];
  #pragma unroll
  for (int j = 0; j < 4; ++j) { mrow[j] = -1e30f; lrow[j] = 0.f; }
  #pragma unroll
  for (int df = 0; df < 8; ++df) oacc[df] = (f32x4){0.f,0.f,0.f,0.f};

  const int kt0 = (i0 >= 512) ? 0 : ((512 - i0) >> 6);
  STAGE_KV(kt0, 0);

  #pragma unroll 1
  for (int kt = kt0; kt < 10; ++kt) {
    const int pb = (kt - kt0) & 1;
    if (kt < 9) { STAGE_KV(kt + 1, pb ^ 1); WVM4; } else { WVM0; }
    BARRIER(); SB0;                          // buf pb published to all waves

    const int base = 512 - kt*64;            // dist = base + r - s
    const int rmin = wv*16;
    if (base + rmin + 15 >= 0 && base + rmin - 63 <= 512) {
      const u16* cK = sK + pb*8192;
      const u16* cV = sV + pb*8192;

      f32x4 s[4];
      #pragma unroll
      for (int nf = 0; nf < 4; ++nf) s[nf] = (f32x4){0.f,0.f,0.f,0.f};
      #pragma unroll
      for (int ks = 0; ks < 4; ++ks) {
        short8 kb[4];
        #pragma unroll
        for (int nf = 0; nf < 4; ++nf) {
          int row = nf*16 + l15;
          int ch = (ks*4 + l4) ^ (row & 15);
          kb[nf] = *(const short8*)(cK + row*128 + ch*8);
        }
        #pragma unroll
        for (int nf = 0; nf < 4; ++nf)
          s[nf] = mfma16(qf[ks], kb[nf], s[nf]);
      }

      if (kt < 2 || kt > 7) {                // edge tiles: 0 <= dist <= 512
        #pragma unroll
        for (int nf = 0; nf < 4; ++nf)
          #pragma unroll
          for (int j = 0; j < 4; ++j) {
            int r = rmin + l4*4 + j;
            int sidx = nf*16 + l15;
            int dist = base + r - sidx;
            if (dist < 0 || dist > 512) s[nf][j] = -1e30f;
          }
      }

      #pragma unroll
      for (int j = 0; j < 4; ++j) {
        float mx = fmaxf(fmaxf(s[0][j], s[1][j]), fmaxf(s[2][j], s[3][j]));
        #pragma unroll
        for (int off = 1; off <= 8; off <<= 1) mx = fmaxf(mx, __shfl_xor(mx, off));
        if (!__all(mx <= mrow[j] + 8.0f)) {  // defer-max: rescale only on growth
          float mnew = fmaxf(mrow[j], mx);
          float scal = __expf(mrow[j] - mnew);
          mrow[j] = mnew;
          lrow[j] *= scal;
          #pragma unroll
          for (int df = 0; df < 8; ++df) oacc[df][j] *= scal;
        }
        float m = mrow[j];
        float ls = 0.f;
        #pragma unroll
        for (int nf = 0; nf < 4; ++nf) {
          float p = __expf(s[nf][j] - m);
          s[nf][j] = p;
          ls += p;
        }
        #pragma unroll
        for (int off = 1; off <= 8; off <<= 1) ls += __shfl_xor(ls, off);
        lrow[j] += ls;
        int prow = l4*4 + j;
        #pragma unroll
        for (int nf = 0; nf < 4; ++nf) {
          int pcol = nf*16 + l15;
          int ch = (pcol >> 3) ^ (prow & 7);
          sPw[prow*64 + ch*8 + (pcol & 7)] = f2bf(s[nf][j]);
        }
      }

      #pragma unroll
      for (int ks2 = 0; ks2 < 2; ++ks2) {
        short8 pa;
        {
          int ch = (ks2*4 + l4) ^ (l15 & 7);
          pa = *(const short8*)(sPw + l15*64 + ch*8);
        }
        #pragma unroll
        for (int df = 0; df < 8; ++df) {
          int vd = df*16 + l15;
          int ch2 = (ks2*4 + l4) ^ (vd & 7);
          short8 vb = *(const short8*)(cV + vd*64 + ch2*8);
          oacc[df] = mfma16(pa, vb, oacc[df]);
        }
      }
    }
    BARRIER();                               // readers of buf pb done
  }

  #pragma unroll
  for (int j = 0; j < 4; ++j) {
    int r = wv*16 + l4*4 + j;
    int i = i0 + r;
    float f = (1.0f / lrow[j]) * gates[((size_t)b*N_ + i)*8 + h];
    #pragma unroll
    for (int df = 0; df < 8; ++df)
      o[((size_t)b*N_ + i)*INNER_ + h*128 + df*16 + l15] = f2bf(oacc[df][j] * f);
  }
#undef STAGE_KV
}

// ---------------------------------------------------------------------------
extern "C" void kernel_launch(void* const* d_in, const int* in_sizes, int n_in,
                              void* d_out, int out_size, void* d_ws, size_t ws_size,
                              hipStream_t stream) {
  const float* x       = (const float*)d_in[0];
  const float* Wq      = (const float*)d_in[1];
  const float* Wkv     = (const float*)d_in[2];
  const float* q_scale = (const float*)d_in[3];
  const float* k_scale = (const float*)d_in[4];
  const float* Wg      = (const float*)d_in[5];
  const float* bg      = (const float*)d_in[6];
  const float* Wo      = (const float*)d_in[7];
  float* out = (float*)d_out;

  u16* qb  = (u16*)d_out;            // q,k,vT inside d_out (50.3 MB of 67 MB)
  u16* kb  = qb + 8388608;
  u16* vTb = kb + 8388608;

  char* w = (char*)d_ws;
  u16* xb   = (u16*)w;               // 33,554,432 B
  u16* ob   = (u16*)w;               // aliases xb (xb dead after gates)
  u16* Wcat = (u16*)(w + 33554432);  // 12,582,912 B
  u16* Wob  = (u16*)(w + 46137344);  // 4,194,304 B
  float* gb = (float*)(w + 50331648);// 262,144 B
  (void)in_sizes; (void)n_in; (void)out_size; (void)ws_size;

  hipFuncSetAttribute((const void*)attn_kernel,
                      hipFuncAttributeMaxDynamicSharedMemorySize, 81920);

  cvt_kernel<<<12288, 256, 0, stream>>>(x, Wq, Wkv, Wo, xb, Wcat, Wob);
  gemm_qkv<<<dim3(24, 64), 256, 0, stream>>>(xb, Wcat, qb, kb, vTb, q_scale, k_scale);
  gates_kernel<<<8192, 256, 0, stream>>>(xb, Wg, bg, gb);
  attn_kernel<<<512, 512, 81920, stream>>>(qb, kb, vTb, gb, ob);
  gemm_proj<<<dim3(16, 64), 256, 0, stream>>>(ob, Wob, out);
}